// Round 1
// baseline (643.747 us; speedup 1.0000x reference)
//
#include <hip/hip_runtime.h>

// RecursiveNN: 3-resolution NCA-style network.
// x0 [16,12,256,256], x1 [16,12,128,128], x2 [16,12,64,64] fp32.
// perceive: per-channel 3x3 stencils (ident, sobel_x, sobel_y, laplacian),
// circular pad; channel layout c*4+f.
// res0: [z0 ; up2(z1)] -> 96x96 conv+bias -> relu -> 12x96 conv
// res1: [z1 ; up2(z2)] -> 96x96 conv+bias -> relu -> 12x96 conv
// res2: z2 -> 96x48 conv+bias -> relu -> 12x96 conv, + x2 residual

namespace {
constexpr int NB = 16;
constexpr int ND = 12;
}

// ---------------- perceive: x [NB,ND,H,W] -> z [NB,4*ND,H,W] ----------------
template<int H, int W, int LH, int LW>
__global__ __launch_bounds__(256)
void perceive_kernel(const float* __restrict__ x, float* __restrict__ z) {
    int idx = blockIdx.x * 256 + threadIdx.x;
    int xx = idx & (W - 1);
    int yy = (idx >> LW) & (H - 1);
    int bc = idx >> (LW + LH);            // b*ND + c
    const float* p = x + bc * H * W;
    int ym = (yy - 1) & (H - 1), yp = (yy + 1) & (H - 1);
    int xm = (xx - 1) & (W - 1), xq = (xx + 1) & (W - 1);
    float n00 = p[ym*W+xm], n01 = p[ym*W+xx], n02 = p[ym*W+xq];
    float n10 = p[yy*W+xm], n11 = p[yy*W+xx], n12 = p[yy*W+xq];
    float n20 = p[yp*W+xm], n21 = p[yp*W+xx], n22 = p[yp*W+xq];
    float sx  = (n02 - n00) + 2.f*(n12 - n10) + (n22 - n20);
    float sy  = (n20 - n00) + 2.f*(n21 - n01) + (n22 - n02);
    float lap = n00 + 2.f*n01 + n02 + 2.f*n10 - 12.f*n11 + 2.f*n12
              + n20 + 2.f*n21 + n22;
    float* zp = z + (bc * 4) * (H * W) + yy * W + xx;
    zp[0]       = n11;
    zp[H*W]     = sx;
    zp[2*H*W]   = sy;
    zp[3*H*W]   = lap;
}

// ---- bilinear 2x upsample taps (jax.image.resize half-pixel + clamp) -------
__device__ __forceinline__ void up_taps(int y, int Hc, int& y0, int& y1, float& t1) {
    int j = y >> 1;
    if (y & 1) { y0 = j;                y1 = min(j + 1, Hc - 1); t1 = 0.25f; }
    else       { y0 = max(j - 1, 0);    y1 = j;                  t1 = 0.75f; }
}

// ---- per-pixel MLP: o[12] = W2 @ relu(W1 @ v + b1); weights via s_loads ----
template<int K>
__device__ __forceinline__ void mlp96(const float* v,
                                      const float* __restrict__ w1,
                                      const float* __restrict__ b1,
                                      const float* __restrict__ w2,
                                      float* o) {
#pragma unroll
    for (int j = 0; j < 12; ++j) o[j] = 0.f;
    for (int oo = 0; oo < 96; ++oo) {
        float a0 = 0.f, a1 = 0.f, a2 = 0.f, a3 = 0.f;
#pragma unroll
        for (int c = 0; c < K; c += 4) {
            a0 += w1[oo*K + c + 0] * v[c + 0];
            a1 += w1[oo*K + c + 1] * v[c + 1];
            a2 += w1[oo*K + c + 2] * v[c + 2];
            a3 += w1[oo*K + c + 3] * v[c + 3];
        }
        float h = fmaxf(b1[oo] + ((a0 + a1) + (a2 + a3)), 0.f);
#pragma unroll
        for (int j = 0; j < 12; ++j) o[j] += w2[j*96 + oo] * h;
    }
}

// ---------------- res0: fused perceive(x0) + up(z1) + MLP -------------------
__global__ __launch_bounds__(256)
void res0_kernel(const float* __restrict__ x0, const float* __restrict__ z1,
                 const float* __restrict__ w1, const float* __restrict__ b1,
                 const float* __restrict__ w2, float* __restrict__ out) {
    constexpr int H = 256, W = 256, Hc = 128, Wc = 128;
    int idx = blockIdx.x * 256 + threadIdx.x;
    int xx = idx & (W - 1);
    int yy = (idx >> 8) & (H - 1);
    int b  = idx >> 16;
    float v[96];
    {   // perceive x0 on the fly -> v[0..47]
        int ym = (yy - 1) & (H - 1), yp = (yy + 1) & (H - 1);
        int xm = (xx - 1) & (W - 1), xq = (xx + 1) & (W - 1);
        const float* bp = x0 + b * ND * H * W;
#pragma unroll
        for (int c = 0; c < ND; ++c) {
            const float* p = bp + c * H * W;
            float n00 = p[ym*W+xm], n01 = p[ym*W+xx], n02 = p[ym*W+xq];
            float n10 = p[yy*W+xm], n11 = p[yy*W+xx], n12 = p[yy*W+xq];
            float n20 = p[yp*W+xm], n21 = p[yp*W+xx], n22 = p[yp*W+xq];
            v[4*c+0] = n11;
            v[4*c+1] = (n02 - n00) + 2.f*(n12 - n10) + (n22 - n20);
            v[4*c+2] = (n20 - n00) + 2.f*(n21 - n01) + (n22 - n02);
            v[4*c+3] = n00 + 2.f*n01 + n02 + 2.f*n10 - 12.f*n11 + 2.f*n12
                     + n20 + 2.f*n21 + n22;
        }
    }
    {   // bilinear up(z1) -> v[48..95]
        int y0, y1, x0i, x1i; float ty, tx;
        up_taps(yy, Hc, y0, y1, ty);
        up_taps(xx, Wc, x0i, x1i, tx);
        float w00 = (1.f-ty)*(1.f-tx), w01 = (1.f-ty)*tx;
        float w10 = ty*(1.f-tx),       w11 = ty*tx;
        const float* r0 = z1 + b * 48 * Hc * Wc;
#pragma unroll
        for (int k = 0; k < 48; ++k) {
            const float* q = r0 + k * Hc * Wc;
            v[48+k] = w00*q[y0*Wc + x0i] + w01*q[y0*Wc + x1i]
                    + w10*q[y1*Wc + x0i] + w11*q[y1*Wc + x1i];
        }
    }
    float o[12];
    mlp96<96>(v, w1, b1, w2, o);
    float* op = out + b * ND * H * W + yy * W + xx;
#pragma unroll
    for (int j = 0; j < 12; ++j) op[j * H * W] = o[j];
}

// ---------------- res1: z1 + up(z2) + MLP -----------------------------------
__global__ __launch_bounds__(256)
void res1_kernel(const float* __restrict__ z1, const float* __restrict__ z2,
                 const float* __restrict__ w1, const float* __restrict__ b1,
                 const float* __restrict__ w2, float* __restrict__ out) {
    constexpr int H = 128, W = 128, Hc = 64, Wc = 64;
    int idx = blockIdx.x * 256 + threadIdx.x;
    int xx = idx & (W - 1);
    int yy = (idx >> 7) & (H - 1);
    int b  = idx >> 14;
    float v[96];
    {
        const float* q = z1 + b * 48 * H * W + yy * W + xx;
#pragma unroll
        for (int k = 0; k < 48; ++k) v[k] = q[k * H * W];
    }
    {
        int y0, y1, x0i, x1i; float ty, tx;
        up_taps(yy, Hc, y0, y1, ty);
        up_taps(xx, Wc, x0i, x1i, tx);
        float w00 = (1.f-ty)*(1.f-tx), w01 = (1.f-ty)*tx;
        float w10 = ty*(1.f-tx),       w11 = ty*tx;
        const float* r0 = z2 + b * 48 * Hc * Wc;
#pragma unroll
        for (int k = 0; k < 48; ++k) {
            const float* q = r0 + k * Hc * Wc;
            v[48+k] = w00*q[y0*Wc + x0i] + w01*q[y0*Wc + x1i]
                    + w10*q[y1*Wc + x0i] + w11*q[y1*Wc + x1i];
        }
    }
    float o[12];
    mlp96<96>(v, w1, b1, w2, o);
    float* op = out + b * ND * H * W + yy * W + xx;
#pragma unroll
    for (int j = 0; j < 12; ++j) op[j * H * W] = o[j];
}

// ---------------- res2: z2 + MLP(K=48) + residual ---------------------------
__global__ __launch_bounds__(256)
void res2_kernel(const float* __restrict__ z2, const float* __restrict__ x2,
                 const float* __restrict__ w1, const float* __restrict__ b1,
                 const float* __restrict__ w2, float* __restrict__ out) {
    constexpr int H = 64, W = 64;
    int idx = blockIdx.x * 256 + threadIdx.x;
    int xx = idx & (W - 1);
    int yy = (idx >> 6) & (H - 1);
    int b  = idx >> 12;
    float v[48];
    {
        const float* q = z2 + b * 48 * H * W + yy * W + xx;
#pragma unroll
        for (int k = 0; k < 48; ++k) v[k] = q[k * H * W];
    }
    float o[12];
    mlp96<48>(v, w1, b1, w2, o);
    const float* rp = x2 + b * ND * H * W + yy * W + xx;
    float* op = out + b * ND * H * W + yy * W + xx;
#pragma unroll
    for (int j = 0; j < 12; ++j) op[j * H * W] = o[j] + rp[j * H * W];
}

extern "C" void kernel_launch(void* const* d_in, const int* in_sizes, int n_in,
                              void* d_out, int out_size, void* d_ws, size_t ws_size,
                              hipStream_t stream) {
    const float* x0   = (const float*)d_in[0];
    const float* x1   = (const float*)d_in[1];
    const float* x2   = (const float*)d_in[2];
    const float* w0_1 = (const float*)d_in[3];
    const float* b0_1 = (const float*)d_in[4];
    const float* w0_2 = (const float*)d_in[5];
    const float* w1_1 = (const float*)d_in[6];
    const float* b1_1 = (const float*)d_in[7];
    const float* w1_2 = (const float*)d_in[8];
    const float* w2_1 = (const float*)d_in[9];
    const float* b2_1 = (const float*)d_in[10];
    const float* w2_2 = (const float*)d_in[11];
    float* out = (float*)d_out;

    float* z1 = (float*)d_ws;                         // [16,48,128,128] = 50.3 MB
    float* z2 = z1 + NB * 48 * 128 * 128;             // [16,48,64,64]   = 12.6 MB

    // perceive coarse levels into workspace
    perceive_kernel<128,128,7,7><<<NB*ND*128*128/256, 256, 0, stream>>>(x1, z1);
    perceive_kernel< 64, 64,6,6><<<NB*ND*64*64/256,   256, 0, stream>>>(x2, z2);

    // fused per-resolution MLPs
    res0_kernel<<<NB*256*256/256, 256, 0, stream>>>(x0, z1, w0_1, b0_1, w0_2, out);
    res1_kernel<<<NB*128*128/256, 256, 0, stream>>>(z1, z2, w1_1, b1_1, w1_2,
                                                    out + NB*ND*256*256);
    res2_kernel<<<NB*64*64/256,   256, 0, stream>>>(z2, x2, w2_1, b2_1, w2_2,
                                                    out + NB*ND*256*256 + NB*ND*128*128);
}

// Round 3
// 219.531 us; speedup vs baseline: 2.9324x; 2.9324x over previous
//
#include <hip/hip_runtime.h>

// RecursiveNN — MFMA formulation, f16 edition (f16 has 10 mantissa bits vs
// bf16's 8; threshold headroom requires it).
// Per 128-pixel block: A[128x96]f16 in LDS (perceive/upsample fused),
// W1 as Bt[n][k] in LDS, mfma 16x16x32 layer1 -> bias+relu -> H (reuse A lds)
// -> mfma layer2 (N=12 padded to 16) -> float4 stores.

namespace {
constexpr int NB = 16;
constexpr int ND = 12;
}

typedef __attribute__((ext_vector_type(8))) _Float16 f16x8;
typedef __attribute__((ext_vector_type(8))) short   s16x8;
typedef __attribute__((ext_vector_type(4))) float   f32x4;

__device__ __forceinline__ unsigned short f2h(float f) {
    return __builtin_bit_cast(unsigned short, (_Float16)f);   // RNE v_cvt_f16_f32
}

// ---------------- perceive: x [NB,ND,H,W] -> z [NB,4*ND,H,W] ----------------
template<int H, int W, int LH, int LW>
__global__ __launch_bounds__(256)
void perceive_kernel(const float* __restrict__ x, float* __restrict__ z) {
    int idx = blockIdx.x * 256 + threadIdx.x;
    int xx = idx & (W - 1);
    int yy = (idx >> LW) & (H - 1);
    int bc = idx >> (LW + LH);            // b*ND + c
    const float* p = x + bc * H * W;
    int ym = (yy - 1) & (H - 1), yp = (yy + 1) & (H - 1);
    int xm = (xx - 1) & (W - 1), xq = (xx + 1) & (W - 1);
    float n00 = p[ym*W+xm], n01 = p[ym*W+xx], n02 = p[ym*W+xq];
    float n10 = p[yy*W+xm], n11 = p[yy*W+xx], n12 = p[yy*W+xq];
    float n20 = p[yp*W+xm], n21 = p[yp*W+xx], n22 = p[yp*W+xq];
    float sx  = (n02 - n00) + 2.f*(n12 - n10) + (n22 - n20);
    float sy  = (n20 - n00) + 2.f*(n21 - n01) + (n22 - n02);
    float lap = n00 + 2.f*n01 + n02 + 2.f*n10 - 12.f*n11 + 2.f*n12
              + n20 + 2.f*n21 + n22;
    float* zp = z + (bc * 4) * (H * W) + yy * W + xx;
    zp[0]       = n11;
    zp[H*W]     = sx;
    zp[2*H*W]   = sy;
    zp[3*H*W]   = lap;
}

// ---- bilinear 2x upsample taps (jax.image.resize half-pixel + clamp) -------
__device__ __forceinline__ void up_taps(int y, int Hc, int& y0, int& y1, float& t1) {
    int j = y >> 1;
    if (y & 1) { y0 = j;                y1 = min(j + 1, Hc - 1); t1 = 0.25f; }
    else       { y0 = max(j - 1, 0);    y1 = j;                  t1 = 0.75f; }
}

// ---------------- fused per-resolution MFMA kernel --------------------------
// RES0: xin=x0 (perceive fused), zc=z1 (upsample)
// RES1: xin=z1 (direct),         zc=z2 (upsample)
// RES2: xin=z2 (direct, K=48 zero-padded to 64), zc=x2 (residual)
template<int RES>
__global__ __launch_bounds__(256, 3)
void res_mfma(const float* __restrict__ xin, const float* __restrict__ zc,
              const float* __restrict__ w1, const float* __restrict__ b1,
              const float* __restrict__ w2, float* __restrict__ out)
{
    constexpr int H  = (RES==0) ? 256 : (RES==1) ? 128 : 64;
    constexpr int W  = H;
    constexpr int LW = (RES==0) ? 8 : (RES==1) ? 7 : 6;
    constexpr int Hc = H/2, Wc = W/2;
    constexpr int HW = H*W;
    constexpr int BPI  = HW/128;           // blocks per image (pow2)
    constexpr int KPAD = (RES==2) ? 64 : 96;   // layer-1 K (padded)
    constexpr int KP   = 104;                  // LDS row stride (f16)

    __shared__ unsigned short Alds[128*KP];    // A, then reused for H
    __shared__ unsigned short W1lds[96*KP];
    __shared__ unsigned short W2lds[16*KP];

    const int tid = threadIdx.x;
    const int gid = blockIdx.x;
    const int b   = gid / BPI;
    const int p0  = (gid - b*BPI) * 128;

    // ---------------- build A in LDS ----------------
    if (RES == 0) {
        // features 0..47: perceive(x0) on the fly
        const float* bp = xin + b * ND * HW;
#pragma unroll
        for (int i = 0; i < 6; ++i) {
            int task = i*256 + tid;            // 128 pix x 12 ch
            int pix = task & 127;
            int c   = task >> 7;
            int pp = p0 + pix;
            int x = pp & (W-1), y = pp >> LW;
            const float* p = bp + c * HW;
            int ym=(y-1)&(H-1), yp=(y+1)&(H-1), xm=(x-1)&(W-1), xq=(x+1)&(W-1);
            float n00=p[ym*W+xm], n01=p[ym*W+x], n02=p[ym*W+xq];
            float n10=p[y*W+xm],  n11=p[y*W+x],  n12=p[y*W+xq];
            float n20=p[yp*W+xm], n21=p[yp*W+x], n22=p[yp*W+xq];
            float sx  = (n02-n00) + 2.f*(n12-n10) + (n22-n20);
            float sy  = (n20-n00) + 2.f*(n21-n01) + (n22-n02);
            float lap = n00+2.f*n01+n02+2.f*n10-12.f*n11+2.f*n12+n20+2.f*n21+n22;
            uint2 pk;
            pk.x = (unsigned)f2h(n11) | ((unsigned)f2h(sx)  << 16);
            pk.y = (unsigned)f2h(sy)  | ((unsigned)f2h(lap) << 16);
            *(uint2*)&Alds[pix*KP + 4*c] = pk;
        }
    } else {
        // features 0..47: direct read (z1 or z2), k-contiguous per half-thread
        int pix = tid >> 1, half = tid & 1;
        int pp = p0 + pix;
        int x = pp & (W-1), y = pp >> LW;
        const float* q0 = xin + b*48*HW + y*W + x;
#pragma unroll
        for (int i = 0; i < 24; ++i) {
            int k = half*24 + i;
            Alds[pix*KP + k] = f2h(q0[k*HW]);
        }
    }

    if (RES != 2) {
        // features 48..95: bilinear upsample of zc
        int pix = tid >> 1, half = tid & 1;
        int pp = p0 + pix;
        int x = pp & (W-1), y = pp >> LW;
        int y0t, y1t, x0t, x1t; float ty, tx;
        up_taps(y, Hc, y0t, y1t, ty);
        up_taps(x, Wc, x0t, x1t, tx);
        float w00 = (1.f-ty)*(1.f-tx), w01 = (1.f-ty)*tx;
        float w10 = ty*(1.f-tx),       w11 = ty*tx;
        const float* r0 = zc + b*48*Hc*Wc;
#pragma unroll
        for (int i = 0; i < 24; ++i) {
            int k = half*24 + i;
            const float* q = r0 + k*Hc*Wc;
            float val = w00*q[y0t*Wc+x0t] + w01*q[y0t*Wc+x1t]
                      + w10*q[y1t*Wc+x0t] + w11*q[y1t*Wc+x1t];
            Alds[pix*KP + 48 + k] = f2h(val);
        }
    } else {
        // zero-pad features 48..63 (K padded to 64)
#pragma unroll
        for (int i = 0; i < 8; ++i) {
            int e = i*256 + tid;               // 128*16
            Alds[(e>>4)*KP + 48 + (e&15)] = 0;
        }
    }

    // ---------------- weights into LDS ----------------
    if (RES != 2) {
        for (int e = tid; e < 96*96; e += 256) {
            int r = e / 96, c = e - r*96;
            W1lds[r*KP + c] = f2h(w1[e]);
        }
    } else {
        for (int e = tid; e < 96*64; e += 256) {
            int r = e >> 6, c = e & 63;
            W1lds[r*KP + c] = (c < 48) ? f2h(w1[r*48 + c]) : (unsigned short)0;
        }
    }
    for (int e = tid; e < 16*KP; e += 256) {
        int r = e / KP, c = e - r*KP;
        float v = (r < 12 && c < 96) ? w2[r*96 + c] : 0.f;
        W2lds[e] = f2h(v);
    }
    __syncthreads();

    // ---------------- layer 1 MFMA ----------------
    const int wid  = tid >> 6;
    const int lane = tid & 63;
    const int fr   = lane & 15;        // row (A) / col (B,D)
    const int g    = lane >> 4;        // k-group
    f32x4 acc[2][6] = {};
    constexpr int NK = KPAD/32;
#pragma unroll
    for (int ks = 0; ks < NK; ++ks) {
        f16x8 a0 = __builtin_bit_cast(f16x8, *(const s16x8*)&Alds[(wid*32 +      fr)*KP + ks*32 + g*8]);
        f16x8 a1 = __builtin_bit_cast(f16x8, *(const s16x8*)&Alds[(wid*32 + 16 + fr)*KP + ks*32 + g*8]);
#pragma unroll
        for (int nt = 0; nt < 6; ++nt) {
            f16x8 bb = __builtin_bit_cast(f16x8, *(const s16x8*)&W1lds[(nt*16 + fr)*KP + ks*32 + g*8]);
            acc[0][nt] = __builtin_amdgcn_mfma_f32_16x16x32_f16(a0, bb, acc[0][nt], 0, 0, 0);
            acc[1][nt] = __builtin_amdgcn_mfma_f32_16x16x32_f16(a1, bb, acc[1][nt], 0, 0, 0);
        }
    }
    __syncthreads();                   // everyone done reading A

    // bias + relu -> H (f16) into Alds
#pragma unroll
    for (int nt = 0; nt < 6; ++nt) {
        float bv = b1[nt*16 + fr];
#pragma unroll
        for (int m = 0; m < 2; ++m) {
#pragma unroll
            for (int rg = 0; rg < 4; ++rg) {
                float h = fmaxf(acc[m][nt][rg] + bv, 0.f);
                Alds[(wid*32 + m*16 + g*4 + rg)*KP + nt*16 + fr] = f2h(h);
            }
        }
    }
    __syncthreads();

    // ---------------- layer 2 MFMA (K=96, N=16 padded) ----------------
    f32x4 acc2[2] = {};
#pragma unroll
    for (int ks = 0; ks < 3; ++ks) {
        f16x8 b2 = __builtin_bit_cast(f16x8, *(const s16x8*)&W2lds[fr*KP + ks*32 + g*8]);
#pragma unroll
        for (int m = 0; m < 2; ++m) {
            f16x8 ah = __builtin_bit_cast(f16x8, *(const s16x8*)&Alds[(wid*32 + m*16 + fr)*KP + ks*32 + g*8]);
            acc2[m] = __builtin_amdgcn_mfma_f32_16x16x32_f16(ah, b2, acc2[m], 0, 0, 0);
        }
    }

    // ---------------- store ----------------
    if (fr < 12) {
#pragma unroll
        for (int m = 0; m < 2; ++m) {
            int pix = p0 + wid*32 + m*16 + g*4;
            float4 vv;
            vv.x = acc2[m][0]; vv.y = acc2[m][1];
            vv.z = acc2[m][2]; vv.w = acc2[m][3];
            if (RES == 2) {
                const float4 rr = *(const float4*)&zc[(b*ND + fr)*HW + pix];
                vv.x += rr.x; vv.y += rr.y; vv.z += rr.z; vv.w += rr.w;
            }
            *(float4*)&out[(b*ND + fr)*HW + pix] = vv;
        }
    }
}

extern "C" void kernel_launch(void* const* d_in, const int* in_sizes, int n_in,
                              void* d_out, int out_size, void* d_ws, size_t ws_size,
                              hipStream_t stream) {
    const float* x0   = (const float*)d_in[0];
    const float* x1   = (const float*)d_in[1];
    const float* x2   = (const float*)d_in[2];
    const float* w0_1 = (const float*)d_in[3];
    const float* b0_1 = (const float*)d_in[4];
    const float* w0_2 = (const float*)d_in[5];
    const float* w1_1 = (const float*)d_in[6];
    const float* b1_1 = (const float*)d_in[7];
    const float* w1_2 = (const float*)d_in[8];
    const float* w2_1 = (const float*)d_in[9];
    const float* b2_1 = (const float*)d_in[10];
    const float* w2_2 = (const float*)d_in[11];
    float* out = (float*)d_out;

    float* z1 = (float*)d_ws;                         // [16,48,128,128]
    float* z2 = z1 + NB * 48 * 128 * 128;             // [16,48,64,64]

    perceive_kernel<128,128,7,7><<<NB*ND*128*128/256, 256, 0, stream>>>(x1, z1);
    perceive_kernel< 64, 64,6,6><<<NB*ND*64*64/256,   256, 0, stream>>>(x2, z2);

    res_mfma<0><<<NB*256*256/128, 256, 0, stream>>>(x0, z1, w0_1, b0_1, w0_2, out);
    res_mfma<1><<<NB*128*128/128, 256, 0, stream>>>(z1, z2, w1_1, b1_1, w1_2,
                                                    out + NB*ND*256*256);
    res_mfma<2><<<NB*64*64/128,   256, 0, stream>>>(z2, x2, w2_1, b2_1, w2_2,
                                                    out + NB*ND*256*256 + NB*ND*128*128);
}